// Round 3
// baseline (27356.912 us; speedup 1.0000x reference)
//
#include <hip/hip_runtime.h>
#include <hip/hip_bf16.h>
#include <hip/hip_cooperative_groups.h>

namespace cg = cooperative_groups;

typedef __bf16 bf16_t;
typedef __bf16 bf16x8 __attribute__((ext_vector_type(8)));
typedef float f32x4 __attribute__((ext_vector_type(4)));

#define TLEN 128
#define BATCHN 512
#define OBS 256
#define HID 1024
#define STATEDIM 1024
#define ROWS (TLEN * BATCHN)   // 65536
#define RKDT 0.25f

enum { EPI_F32 = 0, EPI_GI, EPI_TANH, EPI_K1, EPI_K2, EPI_K3, EPI_K4 };

__device__ __forceinline__ void gload_lds16(const bf16_t* g, bf16_t* l) {
  __builtin_amdgcn_global_load_lds(
      (const __attribute__((address_space(1))) void*)g,
      (__attribute__((address_space(3))) void*)l, 16, 0, 0);
}

__device__ __forceinline__ bf16_t f2bf(float x) { return (bf16_t)x; }

// C = epi(A[M][K] @ Wt[N][K]^T + bias). A,Wt bf16 row-major, fp32 acc.
// m97 structure: 128x128 tile, BK=32, 4 waves (2x2), 16x16x32 MFMA,
// global_load_lds width=16, double-buffered LDS.
template<int EPI>
__global__ __launch_bounds__(256)
void gemm_bt(const bf16_t* __restrict__ A, const bf16_t* __restrict__ Wt,
             const float* __restrict__ bias, int M, int N, int K,
             float* __restrict__ outF, bf16_t* __restrict__ outB,
             float* __restrict__ Z, float* __restrict__ ZN,
             bf16_t* __restrict__ S2)
{
  __shared__ __align__(16) bf16_t As[2][128 * 32];
  __shared__ __align__(16) bf16_t Bs[2][128 * 32];
  const int tid = threadIdx.x;
  const int lane = tid & 63;
  const int wave = tid >> 6;
  const int nbn = N >> 7;
  const int bm = blockIdx.x / nbn;
  const int bn = blockIdx.x % nbn;
  const int m0 = bm << 7, n0 = bn << 7;
  const int wr = wave >> 1, wc = wave & 1;
  const int srow = tid >> 2;          // staging row in tile (0..63)
  const int scol = (tid & 3) << 3;    // staging col (bf16 elems)

  f32x4 acc[4][4] = {};
  const int nk = K >> 5;
  int cur = 0;

  {
    const bf16_t* ga = A  + (size_t)(m0 + srow) * K + scol;
    const bf16_t* gb = Wt + (size_t)(n0 + srow) * K + scol;
    bf16_t* la = &As[0][tid * 8];
    bf16_t* lb = &Bs[0][tid * 8];
    gload_lds16(ga, la);
    gload_lds16(ga + (size_t)64 * K, la + 2048);
    gload_lds16(gb, lb);
    gload_lds16(gb + (size_t)64 * K, lb + 2048);
  }

  for (int ks = 0; ks < nk; ++ks) {
    __syncthreads();  // drains vmcnt(0): staged tile ready
    if (ks + 1 < nk) {
      const bf16_t* ga = A  + (size_t)(m0 + srow) * K + (ks + 1) * 32 + scol;
      const bf16_t* gb = Wt + (size_t)(n0 + srow) * K + (ks + 1) * 32 + scol;
      bf16_t* la = &As[cur ^ 1][tid * 8];
      bf16_t* lb = &Bs[cur ^ 1][tid * 8];
      gload_lds16(ga, la);
      gload_lds16(ga + (size_t)64 * K, la + 2048);
      gload_lds16(gb, lb);
      gload_lds16(gb + (size_t)64 * K, lb + 2048);
    }
    const int kb = (lane >> 4) << 3;
    const int rr = lane & 15;
    bf16x8 af[4], bfr[4];
#pragma unroll
    for (int i = 0; i < 4; ++i) {
      af[i]  = *(const bf16x8*)&As[cur][(wr * 64 + i * 16 + rr) * 32 + kb];
      bfr[i] = *(const bf16x8*)&Bs[cur][(wc * 64 + i * 16 + rr) * 32 + kb];
    }
#pragma unroll
    for (int i = 0; i < 4; ++i)
#pragma unroll
      for (int j = 0; j < 4; ++j)
        acc[i][j] = __builtin_amdgcn_mfma_f32_16x16x32_bf16(af[i], bfr[j], acc[i][j], 0, 0, 0);
    cur ^= 1;
  }

  // C/D layout: col=lane&15, row=(lane>>4)*4+reg  [m89-verified]
  const int cb = n0 + wc * 64 + (lane & 15);
  const int rb = m0 + wr * 64 + ((lane >> 4) << 2);
#pragma unroll
  for (int j = 0; j < 4; ++j) {
    const int c = cb + j * 16;
    float bv = 0.f;
    if constexpr (EPI != EPI_F32) bv = bias[c];
#pragma unroll
    for (int i = 0; i < 4; ++i) {
      const int r0 = rb + i * 16;
#pragma unroll
      for (int r = 0; r < 4; ++r) {
        const size_t idx = (size_t)(r0 + r) * N + c;
        const float v = acc[i][j][r];
        if constexpr (EPI == EPI_F32) {
          outF[idx] = v;
        } else if constexpr (EPI == EPI_GI) {
          outF[idx] = v + bv;
        } else if constexpr (EPI == EPI_TANH) {
          outB[idx] = f2bf(tanhf(v + bv));
        } else {
          const float k = v + bv;          // N==1024 here; idx = row*1024+c
          const size_t si = (size_t)(r0 + r) * 2048 + c;
          float s;
          if constexpr (EPI == EPI_K1) {
            const float z = Z[idx];
            ZN[idx] = z + (RKDT / 6.f) * k;
            s = z + 0.5f * RKDT * k;
          } else if constexpr (EPI == EPI_K2) {
            const float z = Z[idx];
            ZN[idx] += (RKDT / 3.f) * k;
            s = z + 0.5f * RKDT * k;
          } else if constexpr (EPI == EPI_K3) {
            const float z = Z[idx];
            ZN[idx] += (RKDT / 3.f) * k;
            s = z + RKDT * k;
          } else {  // K4
            s = ZN[idx] + (RKDT / 6.f) * k;
            Z[idx] = s;
          }
          const bf16_t hi = f2bf(s);
          S2[si] = hi;
          S2[si + 1024] = f2bf(s - (float)hi);
        }
      }
    }
  }
}

// Persistent GRU: whole recurrence in one cooperative launch.
// grid = 256 blocks (4 row-groups x 64 col-groups), 512 threads (8 waves).
// Block owns rows r0..r0+127, state cols j0..j0+15; Whh slice (3 gates x 16
// cols x 1024) resident in LDS for all steps; h in registers (4 f32/thread);
// split-bf16 h double-buffered in global for the next step's A-operand.
__global__ __launch_bounds__(512)
void gru_persistent(const float* __restrict__ gi,   // [TS][512][3072] (bih included)
                    const bf16_t* __restrict__ Whh, // [3072][1024] bf16
                    const float* __restrict__ bhh,  // [3072]
                    float* __restrict__ Hf,         // [512][1024] f32 persist
                    bf16_t* __restrict__ hb,        // [2][512][2048] split h
                    float* __restrict__ outp,       // d_out (f32)
                    int TS, int t0)
{
  __shared__ __align__(16) bf16_t Bs[48 * 1032];   // pad 1024->1032 (bank spread)
  const int tid  = threadIdx.x;
  const int lane = tid & 63;
  const int w    = tid >> 6;           // wave 0..7 -> rows 16w..16w+15
  const int rg   = blockIdx.x >> 6;    // 0..3
  const int jg   = blockIdx.x & 63;    // 0..63
  const int r0   = rg << 7;
  const int j0   = jg << 4;

  // load Whh slice once: LDS row rr = 16*g + c  <-  Whh[g*1024 + j0 + c][:]
  for (int it = tid; it < 48 * 128; it += 512) {
    const int rr = it >> 7;
    const int co = (it & 127) << 3;
    const int g = rr >> 4, c = rr & 15;
    *(bf16x8*)&Bs[rr * 1032 + co] =
        *(const bf16x8*)&Whh[(size_t)(g * 1024 + j0 + c) * 1024 + co];
  }

  const int myj = j0 + (lane & 15);
  const float bh_r = bhh[myj], bh_z = bhh[1024 + myj], bh_n = bhh[2048 + myj];
  const int rbase = r0 + w * 16 + ((lane >> 4) << 2);

  float h[4];
#pragma unroll
  for (int q = 0; q < 4; ++q) h[q] = Hf[(size_t)(rbase + q) * 1024 + myj];

  __syncthreads();
  cg::grid_group grid = cg::this_grid();

  const int arow = r0 + w * 16 + (lane & 15);     // A-frag row for this lane
  const int akoff = (lane >> 4) << 3;             // A/B k-offset within chunk

  for (int t = t0; t < t0 + TS; ++t) {
    const bf16_t* ap = hb + (size_t)(t & 1) * 512 * 2048 +
                       (size_t)arow * 2048 + akoff;
    f32x4 a0 = {}, a1 = {}, a2 = {};
    const bf16_t* bp0 = &Bs[(0  + (lane & 15)) * 1032 + akoff];
    const bf16_t* bp1 = &Bs[(16 + (lane & 15)) * 1032 + akoff];
    const bf16_t* bp2 = &Bs[(32 + (lane & 15)) * 1032 + akoff];
#pragma unroll 8
    for (int kc = 0; kc < 64; ++kc) {             // K=2048 split (hi|lo), dup-B
      const bf16x8 af = *(const bf16x8*)(ap + kc * 32);
      const int kl = (kc * 32) & 1023;
      a0 = __builtin_amdgcn_mfma_f32_16x16x32_bf16(af, *(const bf16x8*)(bp0 + kl), a0, 0, 0, 0);
      a1 = __builtin_amdgcn_mfma_f32_16x16x32_bf16(af, *(const bf16x8*)(bp1 + kl), a1, 0, 0, 0);
      a2 = __builtin_amdgcn_mfma_f32_16x16x32_bf16(af, *(const bf16x8*)(bp2 + kl), a2, 0, 0, 0);
    }
    // gate (thread-local: C col = lane&15 = myj-j0; row = (lane>>4)*4+q)
    const float* gir = gi + (size_t)(t - t0) * 512 * 3072;
    bf16_t* hbw = hb + (size_t)((t + 1) & 1) * 512 * 2048;
#pragma unroll
    for (int q = 0; q < 4; ++q) {
      const size_t rr = (size_t)(rbase + q);
      const float ir = gir[rr * 3072 + myj];
      const float iz = gir[rr * 3072 + 1024 + myj];
      const float in = gir[rr * 3072 + 2048 + myj];
      const float rg_ = 1.f / (1.f + expf(-(ir + a0[q] + bh_r)));
      const float zg  = 1.f / (1.f + expf(-(iz + a1[q] + bh_z)));
      const float n   = tanhf(in + rg_ * (a2[q] + bh_n));
      h[q] = (1.f - zg) * n + zg * h[q];
      const bf16_t hi = f2bf(h[q]);
      hbw[rr * 2048 + myj] = hi;
      hbw[rr * 2048 + 1024 + myj] = f2bf(h[q] - (float)hi);
    }
    grid.sync();   // one sync/step: dbuf makes this race-free
  }

#pragma unroll
  for (int q = 0; q < 4; ++q) {
    const int r = rbase + q;
    Hf[(size_t)r * 1024 + myj] = h[q];
    if (myj < 512) outp[(size_t)r * 512 + myj] = h[q];
    else           outp[262144 + (size_t)r * 512 + (myj - 512)] = h[q];
  }
}

// per-row LayerNorm(+bias) + LeakyReLU(0.1), row width 1024.
template<bool SPLIT>
__global__ __launch_bounds__(256)
void ln_leaky(const float* __restrict__ pre, const float* __restrict__ b,
              const float* __restrict__ g, const float* __restrict__ bet,
              bf16_t* __restrict__ outB, float* __restrict__ zf)
{
  const int row = blockIdx.x;
  const int tid = threadIdx.x;
  const float* p = pre + (size_t)row * 1024;
  float v[4];
  float s = 0.f, s2 = 0.f;
#pragma unroll
  for (int i = 0; i < 4; ++i) {
    const int c = tid + i * 256;
    v[i] = p[c] + b[c];
    s += v[i]; s2 += v[i] * v[i];
  }
#pragma unroll
  for (int o = 32; o; o >>= 1) { s += __shfl_down(s, o); s2 += __shfl_down(s2, o); }
  __shared__ float rs[4], rs2[4];
  if ((tid & 63) == 0) { rs[tid >> 6] = s; rs2[tid >> 6] = s2; }
  __syncthreads();
  s = rs[0] + rs[1] + rs[2] + rs[3];
  s2 = rs2[0] + rs2[1] + rs2[2] + rs2[3];
  const float mu = s * (1.f / 1024.f);
  const float var = s2 * (1.f / 1024.f) - mu * mu;
  const float rstd = rsqrtf(var + 1e-5f);
#pragma unroll
  for (int i = 0; i < 4; ++i) {
    const int c = tid + i * 256;
    float h = (v[i] - mu) * rstd * g[c] + bet[c];
    h = h >= 0.f ? h : 0.1f * h;
    if constexpr (SPLIT) {
      const bf16_t hi = f2bf(h);
      outB[(size_t)row * 2048 + c] = hi;
      outB[(size_t)row * 2048 + 1024 + c] = f2bf(h - (float)hi);
      zf[(size_t)row * 1024 + c] = h;
    } else {
      outB[(size_t)row * 1024 + c] = f2bf(h);
    }
  }
}

// in[R][C] fp32 -> out[C][R] bf16
__global__ __launch_bounds__(256)
void transpose_bf16(const float* __restrict__ in, bf16_t* __restrict__ out, int R, int C)
{
  __shared__ float t[32][33];
  const int c0 = blockIdx.x * 32, r0 = blockIdx.y * 32;
  const int tx = threadIdx.x & 31, ty = threadIdx.x >> 5;  // 32x8
#pragma unroll
  for (int i = 0; i < 32; i += 8)
    t[ty + i][tx] = in[(size_t)(r0 + ty + i) * C + c0 + tx];
  __syncthreads();
#pragma unroll
  for (int i = 0; i < 32; i += 8)
    out[(size_t)(c0 + ty + i) * R + r0 + tx] = f2bf(t[tx][ty + i]);
}

__global__ __launch_bounds__(256)
void f2b_kernel(const float* __restrict__ in, bf16_t* __restrict__ out, int n)
{
  const int i = blockIdx.x * 256 + threadIdx.x;
  if (i < n) out[i] = f2bf(in[i]);
}

// out[n][2K] = {in[n][K], in[n][K]}  (K-duplication for split-operand GEMMs)
__global__ __launch_bounds__(256)
void dup2_kernel(const bf16_t* __restrict__ in, bf16_t* __restrict__ out, int N, int K)
{
  const int idx = blockIdx.x * 256 + threadIdx.x;
  if (idx >= N * 2 * K) return;
  const int n = idx / (2 * K);
  const int kk = idx - n * 2 * K;
  const int k = kk < K ? kk : kk - K;
  out[idx] = in[(size_t)n * K + k];
}

__global__ void sentinel_kernel(float* out, float code) {
  if (threadIdx.x == 0 && blockIdx.x == 0) out[0] = code;
}

extern "C" void kernel_launch(void* const* d_in, const int* in_sizes, int n_in,
                              void* d_out, int out_size, void* d_ws, size_t ws_size,
                              hipStream_t stream)
{
  const float* xs    = (const float*)d_in[0];
  const float* obs_W = (const float*)d_in[1];
  const float* obs_b = (const float*)d_in[2];
  const float* obs_g = (const float*)d_in[3];
  const float* obs_be= (const float*)d_in[4];
  const float* lat_W = (const float*)d_in[5];
  const float* lat_b = (const float*)d_in[6];
  const float* lat_g = (const float*)d_in[7];
  const float* lat_be= (const float*)d_in[8];
  const float* W0    = (const float*)d_in[9];
  const float* b0    = (const float*)d_in[10];
  const float* W1    = (const float*)d_in[11];
  const float* b1    = (const float*)d_in[12];
  const float* W2    = (const float*)d_in[13];
  const float* b2    = (const float*)d_in[14];
  const float* Wih   = (const float*)d_in[15];
  const float* Whh   = (const float*)d_in[16];
  const float* bih   = (const float*)d_in[17];
  const float* bhh   = (const float*)d_in[18];

  char* ws = (char*)d_ws;
  size_t off = 0;
  auto alloc = [&](size_t bytes) { char* p = ws + off; off += bytes; return p; };

  // ---- static region (~44 MB) ----
  bf16_t* OBSWT = (bf16_t*)alloc((size_t)HID * OBS * 2);
  bf16_t* LATWT = (bf16_t*)alloc((size_t)STATEDIM * HID * 2);
  bf16_t* W0T2  = (bf16_t*)alloc((size_t)HID * 2048 * 2);
  bf16_t* W1T   = (bf16_t*)alloc((size_t)HID * HID * 2);
  bf16_t* W2T   = (bf16_t*)alloc((size_t)STATEDIM * HID * 2);
  bf16_t* WIH2  = (bf16_t*)alloc((size_t)3072 * 2048 * 2);
  bf16_t* WHHB  = (bf16_t*)alloc((size_t)3072 * 1024 * 2);
  float*  Hf    = (float*)alloc((size_t)512 * 1024 * 4);
  bf16_t* HB2   = (bf16_t*)alloc((size_t)2 * 512 * 2048 * 2);
  bf16_t* W0T   = (bf16_t*)alloc((size_t)HID * HID * 2);       // temp
  bf16_t* WIHB  = (bf16_t*)alloc((size_t)3072 * 1024 * 2);     // temp
  const size_t staticEnd = off;

  // ---- choose chunk count: smallest nc whose arena fits ----
  // per-row arena: A1(4096) A2(4096) H1(2048) H2(2048) S2(4096) XSB(512) = 16896 B
  // GI f32 (12288 B/row) overlaps A1+A2+H1+H2 exactly.
  int nc = -1;
  const int ncs[8] = {1, 2, 4, 8, 16, 32, 64, 128};
  for (int i = 0; i < 8; ++i) {
    const size_t R = (size_t)ROWS / ncs[i];
    if (staticEnd + R * 16896 <= ws_size) { nc = ncs[i]; break; }
  }
  if (nc < 0) {
    sentinel_kernel<<<1, 1, 0, stream>>>((float*)d_out,
                                         -(1000000.0f + (float)(ws_size >> 20)));
    return;
  }
  const int R = ROWS / nc;
  char* arena = ws + staticEnd;
  float*  A1f  = (float*)(arena);                       // pre-LN / ZN
  float*  A2f  = (float*)(arena + (size_t)R * 4096);    // z fp32
  bf16_t* H1b  = (bf16_t*)(arena + (size_t)R * 8192);
  bf16_t* H2b  = (bf16_t*)(arena + (size_t)R * 10240);
  bf16_t* S2b  = (bf16_t*)(arena + (size_t)R * 12288);  // split z / stage input
  bf16_t* XSBc = (bf16_t*)(arena + (size_t)R * 16384);
  float*  GIf  = (float*)(arena);                       // gi f32, overlaps A1..H2

  auto gemm = [&](int epi, const bf16_t* A, const bf16_t* Wt, const float* bias,
                  int M, int N, int K, float* oF, bf16_t* oB) {
    dim3 g((M / 128) * (N / 128)), b(256);
    switch (epi) {
      case EPI_F32:  gemm_bt<EPI_F32><<<g, b, 0, stream>>>(A, Wt, bias, M, N, K, oF, oB, A2f, A1f, S2b); break;
      case EPI_GI:   gemm_bt<EPI_GI><<<g, b, 0, stream>>>(A, Wt, bias, M, N, K, oF, oB, A2f, A1f, S2b); break;
      case EPI_TANH: gemm_bt<EPI_TANH><<<g, b, 0, stream>>>(A, Wt, bias, M, N, K, oF, oB, A2f, A1f, S2b); break;
      case EPI_K1:   gemm_bt<EPI_K1><<<g, b, 0, stream>>>(A, Wt, bias, M, N, K, oF, oB, A2f, A1f, S2b); break;
      case EPI_K2:   gemm_bt<EPI_K2><<<g, b, 0, stream>>>(A, Wt, bias, M, N, K, oF, oB, A2f, A1f, S2b); break;
      case EPI_K3:   gemm_bt<EPI_K3><<<g, b, 0, stream>>>(A, Wt, bias, M, N, K, oF, oB, A2f, A1f, S2b); break;
      case EPI_K4:   gemm_bt<EPI_K4><<<g, b, 0, stream>>>(A, Wt, bias, M, N, K, oF, oB, A2f, A1f, S2b); break;
    }
  };

  // ---- weight prep ----
  transpose_bf16<<<dim3(HID / 32, OBS / 32), 256, 0, stream>>>(obs_W, OBSWT, OBS, HID);
  transpose_bf16<<<dim3(STATEDIM / 32, HID / 32), 256, 0, stream>>>(lat_W, LATWT, HID, STATEDIM);
  transpose_bf16<<<dim3(HID / 32, STATEDIM / 32), 256, 0, stream>>>(W0, W0T, STATEDIM, HID);
  dup2_kernel<<<(HID * 2048) / 256, 256, 0, stream>>>(W0T, W0T2, HID, 1024);
  transpose_bf16<<<dim3(HID / 32, HID / 32), 256, 0, stream>>>(W1, W1T, HID, HID);
  transpose_bf16<<<dim3(STATEDIM / 32, HID / 32), 256, 0, stream>>>(W2, W2T, HID, STATEDIM);
  f2b_kernel<<<(3072 * 1024) / 256, 256, 0, stream>>>(Wih, WIHB, 3072 * 1024);
  dup2_kernel<<<(3072 * 2048) / 256, 256, 0, stream>>>(WIHB, WIH2, 3072, 1024);
  f2b_kernel<<<(3072 * 1024) / 256, 256, 0, stream>>>(Whh, WHHB, 3072 * 1024);

  hipMemsetAsync(Hf, 0, (size_t)512 * 1024 * 4, stream);
  hipMemsetAsync(HB2, 0, (size_t)2 * 512 * 2048 * 2, stream);
  const int TS = R / BATCHN;  // timesteps per chunk

  for (int c = 0; c < nc; ++c) {
    // encoder MLPs for this chunk of rows
    f2b_kernel<<<R, 256, 0, stream>>>(xs + (size_t)c * R * OBS, XSBc, R * OBS);
    gemm(EPI_F32, XSBc, OBSWT, nullptr, R, HID, OBS, A1f, nullptr);
    ln_leaky<false><<<R, 256, 0, stream>>>(A1f, obs_b, obs_g, obs_be, H1b, nullptr);
    gemm(EPI_F32, H1b, LATWT, nullptr, R, STATEDIM, HID, A1f, nullptr);
    ln_leaky<true><<<R, 256, 0, stream>>>(A1f, lat_b, lat_g, lat_be, S2b, A2f);

    // RK4: 4 steps x 4 stages x 3 GEMMs, all R rows in parallel
    for (int step = 0; step < 4; ++step) {
      for (int stg = 0; stg < 4; ++stg) {
        gemm(EPI_TANH, S2b, W0T2, b0, R, HID, 2048, nullptr, H1b);
        gemm(EPI_TANH, H1b, W1T, b1, R, HID, HID, nullptr, H2b);
        gemm(EPI_K1 + stg, H2b, W2T, b2, R, STATEDIM, HID, nullptr, nullptr);
      }
    }

    // gi = z_final @ Wih^T + bih (split-z, fp32 out) — overwrites dead A1..H2
    gemm(EPI_GI, S2b, WIH2, bih, R, 3072, 2048, GIf, nullptr);

    // persistent GRU over this chunk's timesteps (one cooperative launch)
    {
      const float* giArg = GIf;
      const bf16_t* whhArg = WHHB;
      const float* bhhArg = bhh;
      float* hfArg = Hf;
      bf16_t* hbArg = HB2;
      float* outArg = (float*)d_out;
      int tsArg = TS;
      int t0Arg = c * TS;
      void* args[] = { (void*)&giArg, (void*)&whhArg, (void*)&bhhArg,
                       (void*)&hfArg, (void*)&hbArg, (void*)&outArg,
                       (void*)&tsArg, (void*)&t0Arg };
      hipLaunchCooperativeKernel((const void*)gru_persistent,
                                 dim3(256), dim3(512), args, 0, stream);
    }
  }
}